// Round 6
// baseline (389.841 us; speedup 1.0000x reference)
//
#include <hip/hip_runtime.h>
#include <hip/hip_bf16.h>
#include <math.h>

#define BB 32
#define NN 128
#define HH 8
#define EE 64
#define CC 16
#define DD 512  // HH*EE

#define NEG_BIG (-1.0e30f)

// ---- bf16 helpers (raw-bit, bf16 -> f32 is a 16-bit shift) ----
__device__ __forceinline__ float bf2f(unsigned short u) {
    union { unsigned int i; float f; } x; x.i = ((unsigned int)u) << 16; return x.f;
}
__device__ __forceinline__ float bflo(unsigned int u) {
    union { unsigned int i; float f; } x; x.i = u << 16; return x.f;
}
__device__ __forceinline__ float bfhi(unsigned int u) {
    union { unsigned int i; float f; } x; x.i = u & 0xffff0000u; return x.f;
}
__device__ __forceinline__ unsigned short f2bf(float f) {
    union { float f; unsigned int i; } x; x.f = f;
    unsigned int r = x.i + 0x7fffu + ((x.i >> 16) & 1u);  // RNE
    return (unsigned short)(r >> 16);
}

template <bool F32>
__device__ __forceinline__ float ldx(const void* p, int i) {
    if constexpr (F32) return ((const float*)p)[i];
    else               return bf2f(((const unsigned short*)p)[i]);
}

// head configs replicated from auto_head_configs(8, 128) (verified by enumeration):
// K = {3,5,3,5,3,5,3,3}, d = {1,5,19,14,37,23,55,63}
// dil packed as bytes of a u64 so the lookup is pure SALU (no memory load).
#define DIL_PACK 0x3F3717250E130501ull

// ---------------- dtype detector: writes flag (1 = f32 inputs, 0 = bf16 inputs) ----
__global__ void detect_dtype(const unsigned short* __restrict__ q, int* __restrict__ flag) {
    const int lane = threadIdx.x;  // 64 threads
    int outliers = 0;
    #pragma unroll
    for (int i = 0; i < 16; ++i) {
        unsigned short u = q[(i * 64 + lane) * 2];
        int e = (u >> 7) & 0xFF;
        int sane = (e >= 101 && e <= 140) || ((u & 0x7FFFu) == 0);
        outliers += !sane;
    }
    #pragma unroll
    for (int m = 32; m >= 1; m >>= 1) outliers += __shfl_xor(outliers, m, 64);
    if (lane == 0) *flag = (outliers > 256) ? 1 : 0;
}

// ---------------- Kernel A: gate = sigmoid(gelu(mean_n(V) @ w1 + b1) @ w2 + b2) ----
// 1024 threads/block (16 waves), dtype branch inside (block-uniform flag read).
template <bool F32>
__device__ __forceinline__ void gate_body(
    const void* __restrict__ values, const void* __restrict__ w1,
    const void* __restrict__ b1, const void* __restrict__ w2,
    const void* __restrict__ b2, float* __restrict__ gate_out,
    float (&vps)[4][DD], float (&vp)[DD], float (&hidp)[4][DD / 4], float (&hid)[DD / 4])
{
    const int bc  = blockIdx.x;       // b*C + c
    const int t   = threadIdx.x;      // 0..1023
    const int grp = t >> 8;           // 0..3: owns 32 of the 128 n-rows
    const int tt  = t & 255;          // owns 2 adjacent d-columns
    float a0 = 0.f, a1 = 0.f;
    if constexpr (F32) {
        const float2* vb = (const float2*)((const float*)values + (size_t)bc * NN * DD)
                           + (size_t)(grp * 32) * (DD / 2);
        #pragma unroll 8
        for (int n = 0; n < 32; ++n) { float2 u = vb[n * (DD / 2) + tt]; a0 += u.x; a1 += u.y; }
    } else {
        const unsigned int* vb = (const unsigned int*)((const unsigned short*)values + (size_t)bc * NN * DD)
                                 + (size_t)(grp * 32) * (DD / 2);
        #pragma unroll 8
        for (int n = 0; n < 32; ++n) { unsigned int u = vb[n * (DD / 2) + tt]; a0 += bflo(u); a1 += bfhi(u); }
    }
    vps[grp][2 * tt]     = a0;
    vps[grp][2 * tt + 1] = a1;
    __syncthreads();
    if (t < 256) {
        float s0 = vps[0][2 * t]     + vps[1][2 * t]     + vps[2][2 * t]     + vps[3][2 * t];
        float s1 = vps[0][2 * t + 1] + vps[1][2 * t + 1] + vps[2][2 * t + 1] + vps[3][2 * t + 1];
        vp[2 * t]     = s0 * (1.0f / NN);
        vp[2 * t + 1] = s1 * (1.0f / NN);
    }
    __syncthreads();
    if (t < 512) {                    // 4-way split of the D-dim dot per hidden unit
        const int o  = t & 127;
        const int ch = t >> 7;
        float a = 0.f;
        #pragma unroll 4
        for (int dd = ch * 128; dd < ch * 128 + 128; ++dd)
            a += vp[dd] * ldx<F32>(w1, dd * (DD / 4) + o);
        hidp[ch][o] = a;
    }
    __syncthreads();
    if (t < 128) {
        float a = ldx<F32>(b1, t) + hidp[0][t] + hidp[1][t] + hidp[2][t] + hidp[3][t];
        hid[t] = 0.5f * a * (1.0f + erff(a * 0.70710678118654752440f));  // exact gelu
    }
    __syncthreads();
    if (t < 64) {
        float s = hid[t] * ldx<F32>(w2, t) + hid[t + 64] * ldx<F32>(w2, t + 64);
        #pragma unroll
        for (int m = 32; m >= 1; m >>= 1) s += __shfl_xor(s, m, 64);
        if (t == 0) {
            float z = s + ldx<F32>(b2, 0);
            gate_out[bc] = 1.0f / (1.0f + expf(-z));
        }
    }
}

__global__ __launch_bounds__(1024) void gate_kernel(
    const void* __restrict__ values, const void* __restrict__ w1,
    const void* __restrict__ b1, const void* __restrict__ w2,
    const void* __restrict__ b2, const int* __restrict__ flag,
    float* __restrict__ gate_out)
{
    __shared__ float vps[4][DD];
    __shared__ float vp[DD];
    __shared__ float hidp[4][DD / 4];
    __shared__ float hid[DD / 4];
    if (*flag) gate_body<true >(values, w1, b1, w2, b2, gate_out, vps, vp, hidp, hid);
    else       gate_body<false>(values, w1, b1, w2, b2, gate_out, vps, vp, hidp, hid);
}

// ---------------- Kernel B: sparse neighborhood attention ----
// DISPATCH-RATE FIX (R5 finding): R1/R3/R4/R5 all pinned at ~96 workgroups/us
// (8192 wg / ~85.5 us) across structurally different kernels -- the attn kernel
// was workgroup-dispatch-rate bound, which is why halving the critical path (R4)
// changed nothing. Now 2048 blocks (dispatch floor ~21 us), each wave processes
// 4 sequential n. Iterations are fully independent: NO LDS, NO fences --
// group g keeps its exo-var c=g end-to-end (per tap: V[c=g] loads in the same
// 16-rows-x-64B pattern as the K loads, FMA with in-register weight), and the
// c-sum is a 15-shuffle butterfly compaction at the end (each lane ends holding
// exactly one output channel).
template <bool F32, int K>
__device__ __forceinline__ void attn_one(
    const void* __restrict__ qptr, const void* __restrict__ kptr,
    const void* __restrict__ vptr, float gv, void* __restrict__ optr,
    int b, int h, int n, int dil, int lane, int g, int sub)
{
    const size_t qoff    = (((size_t)b * NN + n) * HH + h) * EE;
    const size_t kvoff   = ((size_t)b * CC * NN) * DD + (size_t)h * EE;
    const size_t rowbase = kvoff + (size_t)g * NN * DD + (size_t)sub * 16;

    // tap geometry (wave-uniform)
    int  jj[K];
    bool va[K];
    #pragma unroll
    for (int k = 0; k < K; ++k) {
        int j = n + (k - (K >> 1)) * dil;
        va[k] = (j >= 0) && (j < NN);
        jj[k] = j;
    }

    // q slice (16 dims) into registers, scale folded in
    float qreg[16];
    if constexpr (F32) {
        const float4* qp = (const float4*)((const float*)qptr + qoff + sub * 16);
        #pragma unroll
        for (int i = 0; i < 4; ++i) {
            float4 u = qp[i];
            qreg[4 * i + 0] = u.x * 0.125f; qreg[4 * i + 1] = u.y * 0.125f;
            qreg[4 * i + 2] = u.z * 0.125f; qreg[4 * i + 3] = u.w * 0.125f;
        }
    } else {
        const uint4* qp = (const uint4*)((const unsigned short*)qptr + qoff + sub * 16);
        #pragma unroll
        for (int i = 0; i < 2; ++i) {
            uint4 u = qp[i];
            qreg[8 * i + 0] = bflo(u.x) * 0.125f; qreg[8 * i + 1] = bfhi(u.x) * 0.125f;
            qreg[8 * i + 2] = bflo(u.y) * 0.125f; qreg[8 * i + 3] = bfhi(u.y) * 0.125f;
            qreg[8 * i + 4] = bflo(u.z) * 0.125f; qreg[8 * i + 5] = bfhi(u.z) * 0.125f;
            qreg[8 * i + 6] = bflo(u.w) * 0.125f; qreg[8 * i + 7] = bfhi(u.w) * 0.125f;
        }
    }

    // ---- scores: tap k covers all 16 exo vars at wave-uniform j ----
    float s[K];
    #pragma unroll
    for (int k = 0; k < K; ++k) {
        s[k] = NEG_BIG;
        if (va[k]) {                         // wave-uniform branch
            size_t off = rowbase + (size_t)jj[k] * DD;
            float a0 = 0.f, a1 = 0.f, a2 = 0.f, a3 = 0.f;
            if constexpr (F32) {
                const float4* kp = (const float4*)((const float*)kptr + off);
                #pragma unroll
                for (int i = 0; i < 4; ++i) {
                    float4 kk = kp[i];
                    a0 += qreg[4 * i + 0] * kk.x; a1 += qreg[4 * i + 1] * kk.y;
                    a2 += qreg[4 * i + 2] * kk.z; a3 += qreg[4 * i + 3] * kk.w;
                }
            } else {
                const uint4* kp = (const uint4*)((const unsigned short*)kptr + off);
                #pragma unroll
                for (int i = 0; i < 2; ++i) {
                    uint4 kk = kp[i];
                    a0 += qreg[8 * i + 0] * bflo(kk.x); a1 += qreg[8 * i + 1] * bfhi(kk.x);
                    a2 += qreg[8 * i + 2] * bflo(kk.y); a3 += qreg[8 * i + 3] * bfhi(kk.y);
                    a0 += qreg[8 * i + 4] * bflo(kk.z); a1 += qreg[8 * i + 5] * bfhi(kk.z);
                    a2 += qreg[8 * i + 6] * bflo(kk.w); a3 += qreg[8 * i + 7] * bfhi(kk.w);
                }
            }
            float t = (a0 + a1) + (a2 + a3);
            t += __shfl_xor(t, 1, 64);       // 4-lane butterfly -> full dot in all 4 lanes
            t += __shfl_xor(t, 2, 64);
            s[k] = t;
        }
    }

    // ---- softmax in registers (group reduce = shfl over masks 4..32) ----
    float m = s[0];
    #pragma unroll
    for (int k = 1; k < K; ++k) m = fmaxf(m, s[k]);
    #pragma unroll
    for (int mm = 4; mm <= 32; mm <<= 1) m = fmaxf(m, __shfl_xor(m, mm, 64));
    float e[K];
    float ts = 0.f;
    #pragma unroll
    for (int k = 0; k < K; ++k) {
        e[k] = 0.f;
        if (va[k]) { e[k] = expf(s[k] - m); ts += e[k]; }
    }
    #pragma unroll
    for (int mm = 4; mm <= 32; mm <<= 1) ts += __shfl_xor(ts, mm, 64);
    const float inv = 1.0f / ts;

    // ---- V accumulation: this lane owns c=g, channels sub*16..sub*16+15 ----
    float acc[16];
    #pragma unroll
    for (int t = 0; t < 16; ++t) acc[t] = 0.f;
    #pragma unroll
    for (int k = 0; k < K; ++k) {
        if (va[k]) {                         // wave-uniform
            const float wk = e[k] * inv * gv;
            size_t off = rowbase + (size_t)jj[k] * DD;
            if constexpr (F32) {
                const float4* vp4 = (const float4*)((const float*)vptr + off);
                #pragma unroll
                for (int i = 0; i < 4; ++i) {
                    float4 v = vp4[i];
                    acc[4 * i + 0] += wk * v.x; acc[4 * i + 1] += wk * v.y;
                    acc[4 * i + 2] += wk * v.z; acc[4 * i + 3] += wk * v.w;
                }
            } else {
                const uint4* vp4 = (const uint4*)((const unsigned short*)vptr + off);
                #pragma unroll
                for (int i = 0; i < 2; ++i) {
                    uint4 v = vp4[i];
                    acc[8 * i + 0] += wk * bflo(v.x); acc[8 * i + 1] += wk * bfhi(v.x);
                    acc[8 * i + 2] += wk * bflo(v.y); acc[8 * i + 3] += wk * bfhi(v.y);
                    acc[8 * i + 4] += wk * bflo(v.z); acc[8 * i + 5] += wk * bfhi(v.z);
                    acc[8 * i + 6] += wk * bflo(v.w); acc[8 * i + 7] += wk * bfhi(v.w);
                }
            }
        }
    }

    // ---- butterfly compaction over the 16 groups: 15 shfl+add total;
    //      each level halves the channel set while summing across group-bit L.
    int nch = 16;
    #pragma unroll
    for (int L = 0; L < 4; ++L) {
        nch >>= 1;                            // 8,4,2,1
        const int hi = (lane >> (2 + L)) & 1;
        #pragma unroll
        for (int t = 0; t < 8; ++t) {
            if (t < nch) {
                float send = hi ? acc[t] : acc[t + nch];
                float recv = __shfl_xor(send, 4 << L, 64);
                acc[t] = (hi ? acc[t + nch] : acc[t]) + recv;
            }
        }
    }
    // lane (g,sub) now holds channel ch = sub*16 + brev4(g), summed over all c
    const int ch = sub * 16 + (((g & 1) << 3) | ((g & 2) << 1) | ((g & 4) >> 1) | ((g & 8) >> 3));
    if constexpr (F32) ((float*)optr)[qoff + ch] = acc[0];
    else               ((unsigned short*)optr)[qoff + ch] = f2bf(acc[0]);
}

template <bool F32, int K>
__device__ __forceinline__ void attn_quad(
    const void* __restrict__ qptr, const void* __restrict__ kptr,
    const void* __restrict__ vptr, const float* __restrict__ gate,
    void* __restrict__ optr, int b, int h, int n0, int dil, int lane)
{
    const int g   = lane >> 2;               // exo-var c owned by this 4-lane group
    const int sub = lane & 3;                // 16-dim slice of E / channel slice
    const float gv = gate[b * CC + g];       // prefetched once for all 4 n
    #pragma unroll
    for (int i = 0; i < 4; ++i)
        attn_one<F32, K>(qptr, kptr, vptr, gv, optr, b, h, n0 + i, dil, lane, g, sub);
}

__global__ __launch_bounds__(256) void attn_kernel(
    const void* __restrict__ qptr, const void* __restrict__ kptr,
    const void* __restrict__ vptr, const float* __restrict__ gate,
    const int* __restrict__ flag, void* __restrict__ optr)
{
    const int tid  = threadIdx.x;
    const int wave = tid >> 6;
    const int lane = tid & 63;

    // XCD-locality swizzle over 2048 blocks: phys p -> XCD p%8; each XCD gets a
    // contiguous range of (b,h) groups so the per-(b,h) K/V set stays L2-resident.
    const int p    = blockIdx.x;
    const int virt = ((p & 7) << 8) | (p >> 3);
    const int gw0  = virt * 16;             // 16 n-slots per block, same (b,h)
    const int n0   = (gw0 & (NN - 1)) + wave * 4;   // this wave's first n
    const int h    = (gw0 >> 7) & (HH - 1);         // block-uniform
    const int b    = gw0 >> 10;                     // block-uniform
    const int dil  = (int)((DIL_PACK >> (h * 8)) & 0xFF);  // pure SALU lookup
    const bool k5  = (h & 1) && (h != 7);

    const int f = *flag;                     // block-uniform scalar load
    if (f) {
        if (k5) attn_quad<true, 5>(qptr, kptr, vptr, gate, optr, b, h, n0, dil, lane);
        else    attn_quad<true, 3>(qptr, kptr, vptr, gate, optr, b, h, n0, dil, lane);
    } else {
        if (k5) attn_quad<false, 5>(qptr, kptr, vptr, gate, optr, b, h, n0, dil, lane);
        else    attn_quad<false, 3>(qptr, kptr, vptr, gate, optr, b, h, n0, dil, lane);
    }
}

extern "C" void kernel_launch(void* const* d_in, const int* in_sizes, int n_in,
                              void* d_out, int out_size, void* d_ws, size_t ws_size,
                              hipStream_t stream) {
    const void* queries = d_in[0];
    const void* keys    = d_in[1];
    const void* values  = d_in[2];
    const void* w1      = d_in[3];
    const void* b1      = d_in[4];
    const void* w2      = d_in[5];
    const void* b2      = d_in[6];
    // d_in[7] = na_mask: unused — neighborhood structure is regenerated analytically

    int*   flag    = (int*)d_ws;                    // 1 int
    float* gate_ws = (float*)d_ws + 64;             // B*C floats, offset 256 B

    hipLaunchKernelGGL(detect_dtype, dim3(1), dim3(64), 0, stream,
                       (const unsigned short*)queries, flag);
    hipLaunchKernelGGL(gate_kernel, dim3(BB * CC), dim3(1024), 0, stream,
                       values, w1, b1, w2, b2, flag, gate_ws);
    hipLaunchKernelGGL(attn_kernel, dim3(BB * HH * NN / 16), dim3(256), 0, stream,
                       queries, keys, values, gate_ws, flag, d_out);
}

// Round 7
// 336.751 us; speedup vs baseline: 1.1577x; 1.1577x over previous
//
#include <hip/hip_runtime.h>
#include <hip/hip_bf16.h>
#include <math.h>

#define BB 32
#define NN 128
#define HH 8
#define EE 64
#define CC 16
#define DD 512  // HH*EE

#define NEG_BIG (-1.0e30f)

// ---- bf16 helpers (raw-bit, bf16 -> f32 is a 16-bit shift) ----
__device__ __forceinline__ float bf2f(unsigned short u) {
    union { unsigned int i; float f; } x; x.i = ((unsigned int)u) << 16; return x.f;
}
__device__ __forceinline__ float bflo(unsigned int u) {
    union { unsigned int i; float f; } x; x.i = u << 16; return x.f;
}
__device__ __forceinline__ float bfhi(unsigned int u) {
    union { unsigned int i; float f; } x; x.i = u & 0xffff0000u; return x.f;
}
__device__ __forceinline__ unsigned short f2bf(float f) {
    union { float f; unsigned int i; } x; x.f = f;
    unsigned int r = x.i + 0x7fffu + ((x.i >> 16) & 1u);  // RNE
    return (unsigned short)(r >> 16);
}

template <bool F32>
__device__ __forceinline__ float ldx(const void* p, int i) {
    if constexpr (F32) return ((const float*)p)[i];
    else               return bf2f(((const unsigned short*)p)[i]);
}

// head configs replicated from auto_head_configs(8, 128) (verified by enumeration):
// K = {3,5,3,5,3,5,3,3}, d = {1,5,19,14,37,23,55,63}
// dil packed as bytes of a u64 so the lookup is pure SALU (no memory load).
#define DIL_PACK 0x3F3717250E130501ull

// ---------------- dtype detector: writes flag (1 = f32 inputs, 0 = bf16 inputs) ----
__global__ void detect_dtype(const unsigned short* __restrict__ q, int* __restrict__ flag) {
    const int lane = threadIdx.x;  // 64 threads
    int outliers = 0;
    #pragma unroll
    for (int i = 0; i < 16; ++i) {
        unsigned short u = q[(i * 64 + lane) * 2];
        int e = (u >> 7) & 0xFF;
        int sane = (e >= 101 && e <= 140) || ((u & 0x7FFFu) == 0);
        outliers += !sane;
    }
    #pragma unroll
    for (int m = 32; m >= 1; m >>= 1) outliers += __shfl_xor(outliers, m, 64);
    if (lane == 0) *flag = (outliers > 256) ? 1 : 0;
}

// ---------------- Kernel A: gate = sigmoid(gelu(mean_n(V) @ w1 + b1) @ w2 + b2) ----
// 1024 threads/block (16 waves), dtype branch inside (block-uniform flag read).
template <bool F32>
__device__ __forceinline__ void gate_body(
    const void* __restrict__ values, const void* __restrict__ w1,
    const void* __restrict__ b1, const void* __restrict__ w2,
    const void* __restrict__ b2, float* __restrict__ gate_out,
    float (&vps)[4][DD], float (&vp)[DD], float (&hidp)[4][DD / 4], float (&hid)[DD / 4])
{
    const int bc  = blockIdx.x;       // b*C + c
    const int t   = threadIdx.x;      // 0..1023
    const int grp = t >> 8;           // 0..3: owns 32 of the 128 n-rows
    const int tt  = t & 255;          // owns 2 adjacent d-columns
    float a0 = 0.f, a1 = 0.f;
    if constexpr (F32) {
        const float2* vb = (const float2*)((const float*)values + (size_t)bc * NN * DD)
                           + (size_t)(grp * 32) * (DD / 2);
        #pragma unroll 8
        for (int n = 0; n < 32; ++n) { float2 u = vb[n * (DD / 2) + tt]; a0 += u.x; a1 += u.y; }
    } else {
        const unsigned int* vb = (const unsigned int*)((const unsigned short*)values + (size_t)bc * NN * DD)
                                 + (size_t)(grp * 32) * (DD / 2);
        #pragma unroll 8
        for (int n = 0; n < 32; ++n) { unsigned int u = vb[n * (DD / 2) + tt]; a0 += bflo(u); a1 += bfhi(u); }
    }
    vps[grp][2 * tt]     = a0;
    vps[grp][2 * tt + 1] = a1;
    __syncthreads();
    if (t < 256) {
        float s0 = vps[0][2 * t]     + vps[1][2 * t]     + vps[2][2 * t]     + vps[3][2 * t];
        float s1 = vps[0][2 * t + 1] + vps[1][2 * t + 1] + vps[2][2 * t + 1] + vps[3][2 * t + 1];
        vp[2 * t]     = s0 * (1.0f / NN);
        vp[2 * t + 1] = s1 * (1.0f / NN);
    }
    __syncthreads();
    if (t < 512) {                    // 4-way split of the D-dim dot per hidden unit
        const int o  = t & 127;
        const int ch = t >> 7;
        float a = 0.f;
        #pragma unroll 4
        for (int dd = ch * 128; dd < ch * 128 + 128; ++dd)
            a += vp[dd] * ldx<F32>(w1, dd * (DD / 4) + o);
        hidp[ch][o] = a;
    }
    __syncthreads();
    if (t < 128) {
        float a = ldx<F32>(b1, t) + hidp[0][t] + hidp[1][t] + hidp[2][t] + hidp[3][t];
        hid[t] = 0.5f * a * (1.0f + erff(a * 0.70710678118654752440f));  // exact gelu
    }
    __syncthreads();
    if (t < 64) {
        float s = hid[t] * ldx<F32>(w2, t) + hid[t + 64] * ldx<F32>(w2, t + 64);
        #pragma unroll
        for (int m = 32; m >= 1; m >>= 1) s += __shfl_xor(s, m, 64);
        if (t == 0) {
            float z = s + ldx<F32>(b2, 0);
            gate_out[bc] = 1.0f / (1.0f + expf(-z));
        }
    }
}

__global__ __launch_bounds__(1024) void gate_kernel(
    const void* __restrict__ values, const void* __restrict__ w1,
    const void* __restrict__ b1, const void* __restrict__ w2,
    const void* __restrict__ b2, const int* __restrict__ flag,
    float* __restrict__ gate_out)
{
    __shared__ float vps[4][DD];
    __shared__ float vp[DD];
    __shared__ float hidp[4][DD / 4];
    __shared__ float hid[DD / 4];
    if (*flag) gate_body<true >(values, w1, b1, w2, b2, gate_out, vps, vp, hidp, hid);
    else       gate_body<false>(values, w1, b1, w2, b2, gate_out, vps, vp, hidp, hid);
}

// ---------------- Kernel B: sparse neighborhood attention, 1 wave per (b,h,n) ----
// VMEM-INSTRUCTION experiment (R6 finding): R1/R3/R4/R5 all issued ~69 VMEM
// instr/wave (V phase = 50 scalar dword loads) and all ran ~85.5 us -- theory:
// per-CU vector-memory instruction issue/queue is the pipe. This version keeps
// the R5 base (8192 blocks, proven 85.4 us) and changes ONLY the V phase:
// per tap, 4 float4 loads (instr i, lane l: c = 4i + (l>>4), channels
// 4*(l&15)..+3) -- same cache-line count, 4x fewer instructions (wave total
// ~69 -> ~31). Weights reach the new layout via 4 ds_bpermute shuffles per tap
// (source lane 4*c'); lds_w + fence deleted (zero LDS). Final c-sum = 2
// shfl_xor; lanes 0-15 store one float4.
template <bool F32, int K>
__device__ __forceinline__ void attn_body(
    const void* __restrict__ qptr, const void* __restrict__ kptr,
    const void* __restrict__ vptr, const float* __restrict__ gate,
    void* __restrict__ optr,
    int b, int h, int n, int dil, int lane)
{
    constexpr int PRE = (K == 3) ? 3 : 4;   // V taps preloaded before softmax
    const int g    = lane >> 2;             // exo-var c owned by this 4-lane group (scores)
    const int sub  = lane & 3;              // 16-dim slice of E (scores)
    const int crow = lane >> 4;             // V-phase: c-row within instr (0..3)
    const int ch0  = (lane & 15) * 4;       // V-phase: channel base (0..60)

    const size_t qoff  = (((size_t)b * NN + n) * HH + h) * EE;
    const size_t kvoff = ((size_t)b * CC * NN) * DD + (size_t)h * EE;

    // gate prefetch: depends only on (b,g); in flight under scores+softmax
    const float gv = gate[b * CC + g];

    // tap geometry (wave-uniform)
    int  jj[K];
    bool va[K];
    #pragma unroll
    for (int k = 0; k < K; ++k) {
        int j = n + (k - (K >> 1)) * dil;
        va[k] = (j >= 0) && (j < NN);
        jj[k] = j;
    }

    // q slice (16 dims) into registers, scale folded in
    float qreg[16];
    if constexpr (F32) {
        const float4* qp = (const float4*)((const float*)qptr + qoff + sub * 16);
        #pragma unroll
        for (int i = 0; i < 4; ++i) {
            float4 u = qp[i];
            qreg[4 * i + 0] = u.x * 0.125f; qreg[4 * i + 1] = u.y * 0.125f;
            qreg[4 * i + 2] = u.z * 0.125f; qreg[4 * i + 3] = u.w * 0.125f;
        }
    } else {
        const uint4* qp = (const uint4*)((const unsigned short*)qptr + qoff + sub * 16);
        #pragma unroll
        for (int i = 0; i < 2; ++i) {
            uint4 u = qp[i];
            qreg[8 * i + 0] = bflo(u.x) * 0.125f; qreg[8 * i + 1] = bfhi(u.x) * 0.125f;
            qreg[8 * i + 2] = bflo(u.y) * 0.125f; qreg[8 * i + 3] = bfhi(u.y) * 0.125f;
            qreg[8 * i + 4] = bflo(u.z) * 0.125f; qreg[8 * i + 5] = bfhi(u.z) * 0.125f;
            qreg[8 * i + 6] = bflo(u.w) * 0.125f; qreg[8 * i + 7] = bfhi(u.w) * 0.125f;
        }
    }

    // ---- scores in registers: tap k covers all 16 exo vars at wave-uniform j ----
    const size_t rowbase = kvoff + (size_t)g * NN * DD + (size_t)sub * 16;
    float s[K];
    #pragma unroll
    for (int k = 0; k < K; ++k) {
        s[k] = NEG_BIG;
        if (va[k]) {                         // wave-uniform branch
            size_t off = rowbase + (size_t)jj[k] * DD;
            float a0 = 0.f, a1 = 0.f, a2 = 0.f, a3 = 0.f;
            if constexpr (F32) {
                const float4* kp = (const float4*)((const float*)kptr + off);
                #pragma unroll
                for (int i = 0; i < 4; ++i) {
                    float4 kk = kp[i];
                    a0 += qreg[4 * i + 0] * kk.x; a1 += qreg[4 * i + 1] * kk.y;
                    a2 += qreg[4 * i + 2] * kk.z; a3 += qreg[4 * i + 3] * kk.w;
                }
            } else {
                const uint4* kp = (const uint4*)((const unsigned short*)kptr + off);
                #pragma unroll
                for (int i = 0; i < 2; ++i) {
                    uint4 kk = kp[i];
                    a0 += qreg[8 * i + 0] * bflo(kk.x); a1 += qreg[8 * i + 1] * bfhi(kk.x);
                    a2 += qreg[8 * i + 2] * bflo(kk.y); a3 += qreg[8 * i + 3] * bfhi(kk.y);
                    a0 += qreg[8 * i + 4] * bflo(kk.z); a1 += qreg[8 * i + 5] * bfhi(kk.z);
                    a2 += qreg[8 * i + 6] * bflo(kk.w); a3 += qreg[8 * i + 7] * bfhi(kk.w);
                }
            }
            float t = (a0 + a1) + (a2 + a3);
            t += __shfl_xor(t, 1, 64);       // 4-lane butterfly -> full dot in all 4 lanes
            t += __shfl_xor(t, 2, 64);
            s[k] = t;
        }
    }

    // ---- V preload taps 0..PRE-1: 4 float4 loads per tap (4 c-rows x 4 ch) ----
    // lane l covers c = 4i + crow, channels ch0..ch0+3 for instr i.
    float4 vv[PRE][4];       // f32 path
    uint2  vb16[PRE][4];     // bf16 path (4 bf16 per lane per instr)
    #pragma unroll
    for (int k = 0; k < PRE; ++k) {
        if (va[k]) {                         // wave-uniform
            #pragma unroll
            for (int i = 0; i < 4; ++i) {
                size_t off = kvoff + (size_t)(4 * i + crow) * (NN * DD)
                           + (size_t)jj[k] * DD + ch0;
                if constexpr (F32) vv[k][i]   = *(const float4*)((const float*)vptr + off);
                else               vb16[k][i] = *(const uint2*)((const unsigned short*)vptr + off);
            }
        }
    }

    // ---- softmax fully in registers (runs while vv loads are in flight) ----
    float m = s[0];
    #pragma unroll
    for (int k = 1; k < K; ++k) m = fmaxf(m, s[k]);
    #pragma unroll
    for (int mm = 4; mm <= 32; mm <<= 1) m = fmaxf(m, __shfl_xor(m, mm, 64));
    float e[K];
    float ts = 0.f;
    #pragma unroll
    for (int k = 0; k < K; ++k) {
        e[k] = 0.f;
        if (va[k]) { e[k] = expf(s[k] - m); ts += e[k]; }
    }
    #pragma unroll
    for (int mm = 4; mm <= 32; mm <<= 1) ts += __shfl_xor(ts, mm, 64);
    const float inv = 1.0f / ts;

    // ---- late V load for the last tap (K==5 only) ----
    float4 vl[4];
    uint2  vl16[4];
    if constexpr (K == 5) {
        if (va[K - 1]) {
            #pragma unroll
            for (int i = 0; i < 4; ++i) {
                size_t off = kvoff + (size_t)(4 * i + crow) * (NN * DD)
                           + (size_t)jj[K - 1] * DD + ch0;
                if constexpr (F32) vl[i]   = *(const float4*)((const float*)vptr + off);
                else               vl16[i] = *(const uint2*)((const unsigned short*)vptr + off);
            }
        }
    }

    // ---- accumulate: weights via index-shuffle from the score layout ----
    // lane needs w[c'=4i+crow] for tap k; source lane = 4*c' (sub==0 lane of group c').
    float acc0 = 0.f, acc1 = 0.f, acc2 = 0.f, acc3 = 0.f;
    #pragma unroll
    for (int k = 0; k < K; ++k) {
        if (va[k]) {                         // wave-uniform; guards undef vv regs
            const float wk_own = e[k] * inv * gv;
            #pragma unroll
            for (int i = 0; i < 4; ++i) {
                const float w = __shfl(wk_own, 16 * i + 4 * crow, 64);
                if constexpr (F32) {
                    const float4 v = (k < PRE) ? vv[k][i] : vl[i];
                    acc0 += w * v.x; acc1 += w * v.y; acc2 += w * v.z; acc3 += w * v.w;
                } else {
                    const uint2 v = (k < PRE) ? vb16[k][i] : vl16[i];
                    acc0 += w * bflo(v.x); acc1 += w * bfhi(v.x);
                    acc2 += w * bflo(v.y); acc3 += w * bfhi(v.y);
                }
            }
        }
    }

    // ---- c-sum across the 4 crow groups, then lanes 0-15 store float4 ----
    acc0 += __shfl_xor(acc0, 16, 64); acc0 += __shfl_xor(acc0, 32, 64);
    acc1 += __shfl_xor(acc1, 16, 64); acc1 += __shfl_xor(acc1, 32, 64);
    acc2 += __shfl_xor(acc2, 16, 64); acc2 += __shfl_xor(acc2, 32, 64);
    acc3 += __shfl_xor(acc3, 16, 64); acc3 += __shfl_xor(acc3, 32, 64);
    if (lane < 16) {
        if constexpr (F32) {
            float4 r; r.x = acc0; r.y = acc1; r.z = acc2; r.w = acc3;
            ((float4*)((float*)optr + qoff))[lane] = r;
        } else {
            uint2 r;
            r.x = ((unsigned int)f2bf(acc1) << 16) | (unsigned int)f2bf(acc0);
            r.y = ((unsigned int)f2bf(acc3) << 16) | (unsigned int)f2bf(acc2);
            ((uint2*)((unsigned short*)optr + qoff))[lane] = r;
        }
    }
}

__global__ __launch_bounds__(256) void attn_kernel(
    const void* __restrict__ qptr, const void* __restrict__ kptr,
    const void* __restrict__ vptr, const float* __restrict__ gate,
    const int* __restrict__ flag, void* __restrict__ optr)
{
    const int tid  = threadIdx.x;
    const int wave = tid >> 6;
    const int lane = tid & 63;

    // XCD-locality swizzle: phys block p -> XCD p%8 (round-robin assumption).
    // virt = ((p&7)<<10)|(p>>3) gives each XCD a contiguous range of (b,h) groups
    // so the ~1MB per-(b,h) key/value working set stays L2-resident. (R6 showed
    // the 8192-block flow-through also keeps the hot set under the 256MB L3.)
    const int p    = blockIdx.x;
    const int virt = ((p & 7) << 10) | (p >> 3);
    const int gw0  = virt * 4;              // first wave's (b*H + h)*N + n
    const int n    = (gw0 & (NN - 1)) + wave;   // 4 consecutive n, same (b,h)
    const int h    = (gw0 >> 7) & (HH - 1);     // block-uniform
    const int b    = gw0 >> 10;                 // block-uniform
    const int dil  = (int)((DIL_PACK >> (h * 8)) & 0xFF);  // pure SALU lookup
    const bool k5  = (h & 1) && (h != 7);

    const int f = *flag;                     // block-uniform scalar load
    if (f) {
        if (k5) attn_body<true, 5>(qptr, kptr, vptr, gate, optr, b, h, n, dil, lane);
        else    attn_body<true, 3>(qptr, kptr, vptr, gate, optr, b, h, n, dil, lane);
    } else {
        if (k5) attn_body<false, 5>(qptr, kptr, vptr, gate, optr, b, h, n, dil, lane);
        else    attn_body<false, 3>(qptr, kptr, vptr, gate, optr, b, h, n, dil, lane);
    }
}

extern "C" void kernel_launch(void* const* d_in, const int* in_sizes, int n_in,
                              void* d_out, int out_size, void* d_ws, size_t ws_size,
                              hipStream_t stream) {
    const void* queries = d_in[0];
    const void* keys    = d_in[1];
    const void* values  = d_in[2];
    const void* w1      = d_in[3];
    const void* b1      = d_in[4];
    const void* w2      = d_in[5];
    const void* b2      = d_in[6];
    // d_in[7] = na_mask: unused — neighborhood structure is regenerated analytically

    int*   flag    = (int*)d_ws;                    // 1 int
    float* gate_ws = (float*)d_ws + 64;             // B*C floats, offset 256 B

    hipLaunchKernelGGL(detect_dtype, dim3(1), dim3(64), 0, stream,
                       (const unsigned short*)queries, flag);
    hipLaunchKernelGGL(gate_kernel, dim3(BB * CC), dim3(1024), 0, stream,
                       values, w1, b1, w2, b2, flag, gate_ws);
    hipLaunchKernelGGL(attn_kernel, dim3(BB * HH * NN / 4), dim3(256), 0, stream,
                       queries, keys, values, gate_ws, flag, d_out);
}